// Round 1
// baseline (131.728 us; speedup 1.0000x reference)
//
#include <hip/hip_runtime.h>
#include <stdint.h>

typedef unsigned short u16;
typedef __attribute__((ext_vector_type(8))) short short8;
typedef __attribute__((ext_vector_type(4))) float f32x4;

#define S_LEN 2048
#define HID   1024
#define QKV_LD 3072
#define M_ROWS 8192   // B*S

__device__ __forceinline__ u16 f2bf(float f) {
  unsigned u = __float_as_uint(f);
  unsigned r = (u + 0x7fffu + ((u >> 16) & 1u)) >> 16;
  return (u16)r;
}

__device__ __forceinline__ void gload16(const u16* g, u16* l) {
  __builtin_amdgcn_global_load_lds(
      (const __attribute__((address_space(1))) unsigned int*)(g),
      (__attribute__((address_space(3))) unsigned int*)(l),
      16, 0, 0);
}

// ---------------- pack kernels ----------------
__global__ __launch_bounds__(256) void cvt_f32_to_bf16(
    const float* __restrict__ in, u16* __restrict__ out, int n) {
  int i = (blockIdx.x * 256 + threadIdx.x) * 8;
  if (i + 8 > n) return;
  float4 a = *(const float4*)(in + i);
  float4 b = *(const float4*)(in + i + 4);
  u16 t[8];
  t[0] = f2bf(a.x); t[1] = f2bf(a.y); t[2] = f2bf(a.z); t[3] = f2bf(a.w);
  t[4] = f2bf(b.x); t[5] = f2bf(b.y); t[6] = f2bf(b.z); t[7] = f2bf(b.w);
  *(short8*)(out + i) = *(short8*)t;
}

// in: f32 [K][N] row-major; out: bf16 [N][K] row-major
__global__ __launch_bounds__(256) void transpose_to_bf16(
    const float* __restrict__ in, u16* __restrict__ out, int K, int N) {
  __shared__ float tile[32][33];
  int tx = threadIdx.x & 31, ty = threadIdx.x >> 5;
  int n0 = blockIdx.x * 32, k0 = blockIdx.y * 32;
#pragma unroll
  for (int i = 0; i < 32; i += 8)
    tile[ty + i][tx] = in[(size_t)(k0 + ty + i) * N + n0 + tx];
  __syncthreads();
#pragma unroll
  for (int i = 0; i < 32; i += 8)
    out[(size_t)(n0 + ty + i) * K + k0 + tx] = f2bf(tile[tx][ty + i]);
}

__global__ __launch_bounds__(256) void pack_bias(
    const float* __restrict__ bq, const float* __restrict__ bk,
    const float* __restrict__ bv, float* __restrict__ out) {
  int i = blockIdx.x * 256 + threadIdx.x;
  if (i >= 3072) return;
  out[i] = (i < 1024) ? bq[i] : (i < 2048) ? bk[i - 1024] : bv[i - 2048];
}

// ---------------- GEMM: C = A[M,K] * Bt[N,K]^T + bias ----------------
// 128x128 tile, BK=64, 4 waves (2x2), 16x16x32 bf16 MFMA.
// Staging: global_load_lds w=16, linear LDS dest, XOR-pre-swizzled global
// source (slot ^= row&7) so frag ds_read_b128 hits all 32 banks uniformly.
template<int OUT_BF16>
__global__ __launch_bounds__(256, 2) void gemm_bt(
    const u16* __restrict__ A, const u16* __restrict__ Bt,
    const float* __restrict__ bias, void* __restrict__ Cout,
    int M, int N, int K) {
  __shared__ __align__(16) u16 Al[128 * 64];
  __shared__ __align__(16) u16 Bl[128 * 64];
  const int tid = threadIdx.x;
  const int wave = tid >> 6, lane = tid & 63;
  const int nbn = N >> 7;
  int wg = blockIdx.x;
  const int cpx = (int)gridDim.x >> 3;          // grid % 8 == 0 by construction
  wg = (wg & 7) * cpx + (wg >> 3);              // bijective XCD swizzle
  const int bm = wg / nbn, bn = wg % nbn;

  const int wm = wave >> 1, wn = wave & 1;
  const int lrow = lane >> 3;       // 0..7
  const int lslot = lane & 7;       // 0..7
  const int gslot = lslot ^ lrow;   // inverse-swizzled source slot
  const int qlane = lane & 15, kgrp = lane >> 4;

  size_t a_off[4], b_off[4];
  u16 *al_base[4], *bl_base[4];
#pragma unroll
  for (int t = 0; t < 4; ++t) {
    int rr = (wave * 4 + t) * 8 + lrow;
    a_off[t] = (size_t)(bm * 128 + rr) * K + gslot * 8;
    b_off[t] = (size_t)(bn * 128 + rr) * K + gslot * 8;
    al_base[t] = Al + (wave * 4 + t) * 512;
    bl_base[t] = Bl + (wave * 4 + t) * 512;
  }

  f32x4 acc[4][4] = {};
  for (int kt = 0; kt < K; kt += 64) {
#pragma unroll
    for (int t = 0; t < 4; ++t) {
      gload16(A + a_off[t] + kt, al_base[t]);
      gload16(Bt + b_off[t] + kt, bl_base[t]);
    }
    __syncthreads();   // drains vmcnt (global_load_lds) + lgkm
#pragma unroll
    for (int kk = 0; kk < 2; ++kk) {
      short8 af[4], bf[4];
#pragma unroll
      for (int mf = 0; mf < 4; ++mf) {
        int row = wm * 64 + mf * 16 + qlane;
        int s = (kk * 4 + kgrp) ^ (row & 7);
        af[mf] = *(const short8*)&Al[row * 64 + s * 8];
      }
#pragma unroll
      for (int nf = 0; nf < 4; ++nf) {
        int row = wn * 64 + nf * 16 + qlane;
        int s = (kk * 4 + kgrp) ^ (row & 7);
        bf[nf] = *(const short8*)&Bl[row * 64 + s * 8];
      }
#pragma unroll
      for (int mf = 0; mf < 4; ++mf)
#pragma unroll
        for (int nf = 0; nf < 4; ++nf)
          acc[mf][nf] = __builtin_amdgcn_mfma_f32_16x16x32_bf16(
              af[mf], bf[nf], acc[mf][nf], 0, 0, 0);
    }
    __syncthreads();
  }

#pragma unroll
  for (int nf = 0; nf < 4; ++nf) {
    int col = bn * 128 + wn * 64 + nf * 16 + qlane;
    float bv = bias[col];
#pragma unroll
    for (int mf = 0; mf < 4; ++mf) {
      int row0 = bm * 128 + wm * 64 + mf * 16 + kgrp * 4;
#pragma unroll
      for (int r = 0; r < 4; ++r) {
        float v = acc[mf][nf][r] + bv;
        if (OUT_BF16)
          ((u16*)Cout)[(size_t)(row0 + r) * N + col] = f2bf(v);
        else
          ((float*)Cout)[(size_t)(row0 + r) * N + col] = v;
      }
    }
  }
}

// ---------------- banded local attention ----------------
// qkv: bf16 [B*S][3072] (Q|K|V), aout: bf16 [B*S][1024]
// block = 256 thr (4 waves); each block: one (b,h) x 128 queries.
// wave handles 32 queries; its keys = 96-row window starting at wave*32
// within the block's 192-row key tile (jt = qs0-32).
__global__ __launch_bounds__(256, 2) void attn_local(
    const u16* __restrict__ qkv, const int* __restrict__ amask,
    u16* __restrict__ aout) {
  __shared__ __align__(16) u16 Kl[192][72];
  __shared__ __align__(16) u16 Vt[64][200];
  __shared__ __align__(16) u16 Pl[4][32][104];

  const int tid = threadIdx.x, wave = tid >> 6, lane = tid & 63;
  const int qlane = lane & 15, kgrp = lane >> 4;
  const int bz = blockIdx.x;
  const int qt = bz & 15, h = (bz >> 4) & 15, b = bz >> 8;
  const int qs0 = qt * 128;
  const int jt = qs0 - 32;
  const size_t rbase = (size_t)b * S_LEN;

  // stage K tile and V^T tile
  {
    const int r0 = tid >> 3, c0 = (tid & 7) * 8;
#pragma unroll
    for (int p = 0; p < 6; ++p) {
      int row = p * 32 + r0;
      int j = jt + row;
      u16 kv[8], vv[8];
      if (j >= 0 && j < S_LEN) {
        const u16* kp = qkv + (rbase + j) * QKV_LD + HID + h * 64 + c0;
        *(short8*)kv = *(const short8*)kp;
        *(short8*)vv = *(const short8*)(kp + HID);
      } else {
#pragma unroll
        for (int q = 0; q < 8; ++q) { kv[q] = 0; vv[q] = 0; }
      }
      *(short8*)&Kl[row][c0] = *(short8*)kv;
#pragma unroll
      for (int q = 0; q < 8; ++q) Vt[c0 + q][row] = vv[q];
    }
  }

  // Q fragments from global (registers)
  short8 qf[2][2];
#pragma unroll
  for (int mf = 0; mf < 2; ++mf)
#pragma unroll
    for (int kk = 0; kk < 2; ++kk)
      qf[mf][kk] = *(const short8*)(qkv +
          (rbase + qs0 + wave * 32 + mf * 16 + qlane) * QKV_LD +
          h * 64 + kk * 32 + kgrp * 8);

  __syncthreads();

  // scores: S[32 q][96 j] per wave
  f32x4 sc[2][6] = {};
#pragma unroll
  for (int kk = 0; kk < 2; ++kk) {
    short8 kf[6];
#pragma unroll
    for (int nf = 0; nf < 6; ++nf)
      kf[nf] = *(const short8*)&Kl[wave * 32 + nf * 16 + qlane][kk * 32 + kgrp * 8];
#pragma unroll
    for (int mf = 0; mf < 2; ++mf)
#pragma unroll
      for (int nf = 0; nf < 6; ++nf)
        sc[mf][nf] = __builtin_amdgcn_mfma_f32_16x16x32_bf16(
            qf[mf][kk], kf[nf], sc[mf][nf], 0, 0, 0);
  }

  int jcol[6], mv[6];
#pragma unroll
  for (int nf = 0; nf < 6; ++nf) {
    int j = jt + wave * 32 + nf * 16 + qlane;
    jcol[nf] = j;
    mv[nf] = (j >= 0 && j < S_LEN) ? amask[rbase + j] : 0;
  }

  float inv[2][4];
#pragma unroll
  for (int mf = 0; mf < 2; ++mf) {
    const int irow0 = qs0 + wave * 32 + mf * 16 + kgrp * 4;
    float mx[4] = {-1e30f, -1e30f, -1e30f, -1e30f};
#pragma unroll
    for (int r = 0; r < 4; ++r) {
      int i = irow0 + r;
#pragma unroll
      for (int nf = 0; nf < 6; ++nf) {
        int d = i - jcol[nf];
        if (mv[nf] && d >= -32 && d <= 32) mx[r] = fmaxf(mx[r], sc[mf][nf][r]);
      }
    }
#pragma unroll
    for (int m = 1; m < 16; m <<= 1)
#pragma unroll
      for (int r = 0; r < 4; ++r)
        mx[r] = fmaxf(mx[r], __shfl_xor(mx[r], m));
    float sm[4] = {0.f, 0.f, 0.f, 0.f};
#pragma unroll
    for (int r = 0; r < 4; ++r) {
      int i = irow0 + r;
#pragma unroll
      for (int nf = 0; nf < 6; ++nf) {
        int d = i - jcol[nf];
        bool val = mv[nf] && d >= -32 && d <= 32;
        float p = val ? __expf((sc[mf][nf][r] - mx[r]) * 0.125f) : 0.f;
        sc[mf][nf][r] = p;
        sm[r] += p;
      }
    }
#pragma unroll
    for (int m = 1; m < 16; m <<= 1)
#pragma unroll
      for (int r = 0; r < 4; ++r)
        sm[r] += __shfl_xor(sm[r], m);
#pragma unroll
    for (int r = 0; r < 4; ++r)
      inv[mf][r] = sm[r] > 0.f ? 1.f / sm[r] : 0.f;
#pragma unroll
    for (int nf = 0; nf < 6; ++nf)
#pragma unroll
      for (int r = 0; r < 4; ++r)
        Pl[wave][mf * 16 + kgrp * 4 + r][nf * 16 + qlane] = f2bf(sc[mf][nf][r]);
  }
  __syncthreads();

  // PV: O[32 q][64 d] per wave, K=96
  f32x4 oc[2][4] = {};
#pragma unroll
  for (int ks = 0; ks < 3; ++ks) {
    short8 pa[2], vb[4];
#pragma unroll
    for (int mf = 0; mf < 2; ++mf)
      pa[mf] = *(const short8*)&Pl[wave][mf * 16 + qlane][ks * 32 + kgrp * 8];
#pragma unroll
    for (int nf = 0; nf < 4; ++nf)
      vb[nf] = *(const short8*)&Vt[nf * 16 + qlane][wave * 32 + ks * 32 + kgrp * 8];
#pragma unroll
    for (int mf = 0; mf < 2; ++mf)
#pragma unroll
      for (int nf = 0; nf < 4; ++nf)
        oc[mf][nf] = __builtin_amdgcn_mfma_f32_16x16x32_bf16(
            pa[mf], vb[nf], oc[mf][nf], 0, 0, 0);
  }

#pragma unroll
  for (int mf = 0; mf < 2; ++mf)
#pragma unroll
    for (int nf = 0; nf < 4; ++nf)
#pragma unroll
      for (int r = 0; r < 4; ++r) {
        size_t row = rbase + qs0 + wave * 32 + mf * 16 + kgrp * 4 + r;
        aout[row * HID + h * 64 + nf * 16 + qlane] =
            f2bf(oc[mf][nf][r] * inv[mf][r]);
      }
}

// ---------------- launch ----------------
extern "C" void kernel_launch(void* const* d_in, const int* in_sizes, int n_in,
                              void* d_out, int out_size, void* d_ws, size_t ws_size,
                              hipStream_t stream) {
  const float* x  = (const float*)d_in[0];
  const int* amask = (const int*)d_in[1];
  const float* Wq = (const float*)d_in[2];
  const float* bq = (const float*)d_in[3];
  const float* Wk = (const float*)d_in[4];
  const float* bk = (const float*)d_in[5];
  const float* Wv = (const float*)d_in[6];
  const float* bv = (const float*)d_in[7];
  const float* Wo = (const float*)d_in[8];
  const float* bo = (const float*)d_in[9];
  float* out = (float*)d_out;

  char* w = (char*)d_ws;
  u16* xb    = (u16*)w;   w += (size_t)M_ROWS * HID * 2;
  u16* wqkvt = (u16*)w;   w += (size_t)3072 * 1024 * 2;
  u16* wot   = (u16*)w;   w += (size_t)1024 * 1024 * 2;
  float* bqkv = (float*)w; w += 3072 * 4 + 256;
  u16* qkv   = (u16*)w;   w += (size_t)M_ROWS * 3072 * 2;
  u16* aout  = (u16*)w;   w += (size_t)M_ROWS * HID * 2;

  cvt_f32_to_bf16<<<4096, 256, 0, stream>>>(x, xb, M_ROWS * HID);
  dim3 tg(32, 32);
  transpose_to_bf16<<<tg, 256, 0, stream>>>(Wq, wqkvt,                1024, 1024);
  transpose_to_bf16<<<tg, 256, 0, stream>>>(Wk, wqkvt + 1024 * 1024,  1024, 1024);
  transpose_to_bf16<<<tg, 256, 0, stream>>>(Wv, wqkvt + 2048 * 1024,  1024, 1024);
  transpose_to_bf16<<<tg, 256, 0, stream>>>(Wo, wot,                  1024, 1024);
  pack_bias<<<12, 256, 0, stream>>>(bq, bk, bv, bqkv);

  gemm_bt<1><<<64 * 24, 256, 0, stream>>>(xb, wqkvt, bqkv, qkv, M_ROWS, 3072, 1024);
  attn_local<<<1024, 256, 0, stream>>>(qkv, amask, aout);
  gemm_bt<0><<<64 * 8, 256, 0, stream>>>(aout, wot, bo, out, M_ROWS, 1024, 1024);
}